// Round 16
// baseline (272.693 us; speedup 1.0000x reference)
//
#include <hip/hip_runtime.h>
#include <hip/hip_bf16.h>
#include <math.h>

#define T_SEQ 2048
#define NB 2
#define C_DIM 768
#define NH 12

typedef unsigned short ushort_t;
typedef __attribute__((ext_vector_type(8))) short short8;
typedef __attribute__((ext_vector_type(8))) unsigned short ushort8;
typedef __attribute__((ext_vector_type(4))) unsigned short ushortx4;
typedef __attribute__((ext_vector_type(4))) float floatx4;
typedef __attribute__((ext_vector_type(4))) _Float16 half4;

__device__ inline float bf2f(ushort_t u) {
    unsigned int x = ((unsigned int)u) << 16;
    return __uint_as_float(x);
}
__device__ inline ushort_t f2bf(float f) {
    unsigned int u = __float_as_uint(f);
    unsigned int r = (u + 0x7fffu + ((u >> 16) & 1u)) >> 16;
    return (ushort_t)r;
}
__device__ inline ushort_t f2h_bits(float f) {
    union { _Float16 h; ushort_t u; } cv;
    cv.h = (_Float16)f;
    return cv.u;
}

#if defined(__has_builtin)
#if __has_builtin(__builtin_amdgcn_global_load_lds)
#define HAVE_GLL 1
#endif
#endif

__device__ inline void gload_lds16(const ushort_t* g, ushort_t* l) {
#ifdef HAVE_GLL
    __builtin_amdgcn_global_load_lds(
        (const __attribute__((address_space(1))) void*)g,
        (__attribute__((address_space(3))) void*)l, 16, 0, 0);
#else
    int lane = threadIdx.x & 63;
    *(ushort8*)(l + lane * 8) = *(const ushort8*)g;
#endif
}

// ------------- wconv tile: W[K][N] fp32 -> WT[N][K] bf16, one 64x64 tile -------------
__device__ void wconv_tile(const float* __restrict__ W, ushort_t* __restrict__ WT,
                           int K, int N, int k0, int n0, int tid, ushort_t* Tls) {
    int nl = (tid & 15) * 4;
    int kl = tid >> 4;
#pragma unroll
    for (int rr = 0; rr < 4; rr++) {
        int k = kl + rr * 16;
        floatx4 v = *(const floatx4*)&W[(size_t)(k0 + k) * N + n0 + nl];
#pragma unroll
        for (int j = 0; j < 4; j++) Tls[(nl + j) * 72 + k] = f2bf(v[j]);
    }
    __syncthreads();
    int no = tid >> 3;
    int ko = (tid & 7) * 8;
#pragma unroll
    for (int rr = 0; rr < 2; rr++) {
        int n = no + rr * 32;
        ushort8 t = *(const ushort8*)&Tls[n * 72 + ko];
        *(ushort8*)&WT[(size_t)(n0 + n) * K + k0 + ko] = t;
    }
}

// ---- prep1: all 4 weight conversions + LN1, routed by block range ----
__global__ __launch_bounds__(256) void prep1_kernel(const float* __restrict__ w_qkv, ushort_t* __restrict__ wqkvT,
                                                    const float* __restrict__ w_o, ushort_t* __restrict__ woT,
                                                    const float* __restrict__ w_fc, ushort_t* __restrict__ wfcT,
                                                    const float* __restrict__ w_proj, ushort_t* __restrict__ wprojT,
                                                    const float* __restrict__ x, const float* __restrict__ g,
                                                    const float* __restrict__ b, ushort_t* __restrict__ xn) {
    __shared__ ushort_t Tls[64 * 72];
    __shared__ float red[8];
    int id = blockIdx.x, tid = threadIdx.x;
    if (id < 432) { wconv_tile(w_qkv, wqkvT, 768, 2304, (id % 12) * 64, (id / 12) * 64, tid, Tls); return; }
    if (id < 576) { int r = id - 432; wconv_tile(w_o, woT, 768, 768, (r % 12) * 64, (r / 12) * 64, tid, Tls); return; }
    if (id < 1152) { int r = id - 576; wconv_tile(w_fc, wfcT, 768, 3072, (r % 12) * 64, (r / 12) * 64, tid, Tls); return; }
    if (id < 1728) { int r = id - 1152; wconv_tile(w_proj, wprojT, 3072, 768, (r % 48) * 64, (r / 48) * 64, tid, Tls); return; }
    int row = id - 1728;
    int lane = tid & 63, wave = tid >> 6;
    const float* xr = x + (size_t)row * C_DIM;
    float v0 = xr[tid], v1 = xr[tid + 256], v2 = xr[tid + 512];
    float s = v0 + v1 + v2;
#pragma unroll
    for (int m = 32; m > 0; m >>= 1) s += __shfl_xor(s, m, 64);
    if (lane == 0) red[wave] = s;
    __syncthreads();
    float mean = (red[0] + red[1] + red[2] + red[3]) * (1.0f / C_DIM);
    float d0 = v0 - mean, d1 = v1 - mean, d2 = v2 - mean;
    float q = d0 * d0 + d1 * d1 + d2 * d2;
#pragma unroll
    for (int m = 32; m > 0; m >>= 1) q += __shfl_xor(q, m, 64);
    if (lane == 0) red[wave + 4] = q;
    __syncthreads();
    float var = (red[4] + red[5] + red[6] + red[7]) * (1.0f / C_DIM);
    float rstd = rsqrtf(var + 1e-5f);
    ushort_t* orow = xn + (size_t)row * C_DIM;
    orow[tid]       = f2bf(d0 * rstd * g[tid]       + b[tid]);
    orow[tid + 256] = f2bf(d1 * rstd * g[tid + 256] + b[tid + 256]);
    orow[tid + 512] = f2bf(d2 * rstd * g[tid + 512] + b[tid + 512]);
}

// ---- Fused: x2 = x + P0+P1+P2 (fp32) then LayerNorm -> xn (bf16). 192 thr/row ----
__global__ __launch_bounds__(192) void combine_ln_kernel(const float* __restrict__ x,
                                                         const ushort_t* __restrict__ P,
                                                         const float* __restrict__ g,
                                                         const float* __restrict__ bb,
                                                         float* __restrict__ x2,
                                                         ushort_t* __restrict__ xn) {
    int row = blockIdx.x;
    int tid = threadIdx.x;
    int lane = tid & 63, wave = tid >> 6;
    int col = tid * 4;
    size_t idx = (size_t)row * C_DIM + col;
    floatx4 xv = *(const floatx4*)&x[idx];
    ushortx4 a = *(const ushortx4*)&P[idx];
    ushortx4 b2 = *(const ushortx4*)&P[3145728 + idx];
    ushortx4 c2 = *(const ushortx4*)&P[6291456 + idx];
    floatx4 v;
#pragma unroll
    for (int j = 0; j < 4; j++) v[j] = xv[j] + bf2f(a[j]) + bf2f(b2[j]) + bf2f(c2[j]);
    *(floatx4*)&x2[idx] = v;

    float s = v[0] + v[1] + v[2] + v[3];
#pragma unroll
    for (int m = 32; m > 0; m >>= 1) s += __shfl_xor(s, m, 64);
    __shared__ float red[6];
    if (lane == 0) red[wave] = s;
    __syncthreads();
    float mean = (red[0] + red[1] + red[2]) * (1.0f / C_DIM);
    floatx4 d;
#pragma unroll
    for (int j = 0; j < 4; j++) d[j] = v[j] - mean;
    float q = d[0] * d[0] + d[1] * d[1] + d[2] * d[2] + d[3] * d[3];
#pragma unroll
    for (int m = 32; m > 0; m >>= 1) q += __shfl_xor(q, m, 64);
    if (lane == 0) red[wave + 3] = q;
    __syncthreads();
    float var = (red[3] + red[4] + red[5]) * (1.0f / C_DIM);
    float rstd = rsqrtf(var + 1e-5f);
    floatx4 gv = *(const floatx4*)&g[col];
    floatx4 bv = *(const floatx4*)&bb[col];
    ushortx4 o;
#pragma unroll
    for (int j = 0; j < 4; j++) o[j] = f2bf(d[j] * rstd * gv[j] + bv[j]);
    *(ushortx4*)&xn[idx] = o;
}

// ======== GEMM K-loop v3: 128x64 tile, BK=32, dbuf LDS (24 KB -> 6 blocks/CU) ========
// Grid-starvation fix: smaller N-tile doubles block count so barrier stalls of one
// block are hidden by others. Staging: 12 chunks (A:8, B:4), 3 per wave, swizzled as v2.
#define GEMM_LOOP3(Aptr, Bptr, KDIM, KLEN, KOFF)                                       \
    __shared__ ushort_t As[2][4096];                                                   \
    __shared__ ushort_t Bs[2][2048];                                                   \
    int tid = threadIdx.x;                                                             \
    int lane = tid & 63, wave = tid >> 6;                                              \
    int lane15 = lane & 15, quad = lane >> 4;                                          \
    int row0 = blockIdx.x * 128, col0 = blockIdx.y * 64;                               \
    const ushort_t* sp[3];                                                             \
    ushort_t* dp[2][3];                                                                \
    _Pragma("unroll")                                                                  \
    for (int j = 0; j < 3; j++) {                                                      \
        int ch = wave * 3 + j;                                                         \
        bool isA = (ch < 8);                                                           \
        int cb = isA ? ch : ch - 8;                                                    \
        int g = cb * 64 + lane;                                                        \
        int row = g >> 2, j2 = g & 3;                                                  \
        int s = (j2 - (row >> 1)) & 3;                                                 \
        const ushort_t* Mp = isA ? (Aptr) : (Bptr);                                    \
        int rb = isA ? row0 : col0;                                                    \
        sp[j] = Mp + (size_t)(rb + row) * (KDIM) + (KOFF) + s * 8;                     \
        dp[0][j] = isA ? &As[0][cb * 512] : &Bs[0][cb * 512];                          \
        dp[1][j] = isA ? &As[1][cb * 512] : &Bs[1][cb * 512];                          \
    }                                                                                  \
    floatx4 acc[2][4];                                                                 \
    {                                                                                  \
        floatx4 zz = {0.f, 0.f, 0.f, 0.f};                                             \
        _Pragma("unroll")                                                              \
        for (int mt = 0; mt < 2; mt++)                                                 \
            _Pragma("unroll")                                                          \
            for (int nt = 0; nt < 4; nt++) acc[mt][nt] = zz;                           \
    }                                                                                  \
    _Pragma("unroll")                                                                  \
    for (int j = 0; j < 3; j++) gload_lds16(sp[j], dp[0][j]);                          \
    int n_tiles = (KLEN) / 32;                                                         \
    for (int t = 0; t < n_tiles; t++) {                                                \
        int cur = t & 1;                                                               \
        __syncthreads();                                                               \
        if (t + 1 < n_tiles) {                                                         \
            _Pragma("unroll")                                                          \
            for (int j = 0; j < 3; j++)                                                \
                gload_lds16(sp[j] + (t + 1) * 32, dp[cur ^ 1][j]);                     \
        }                                                                              \
        const ushort_t* Ac = As[cur];                                                  \
        const ushort_t* Bc = Bs[cur];                                                  \
        short8 af[2], bfm[4];                                                          \
        _Pragma("unroll")                                                              \
        for (int mt = 0; mt < 2; mt++) {                                               \
            int ra = wave * 32 + mt * 16 + lane15;                                     \
            af[mt] = *(const short8*)&Ac[ra * 32 + (((quad + (ra >> 1)) & 3) << 3)];   \
        }                                                                              \
        _Pragma("unroll")                                                              \
        for (int nt = 0; nt < 4; nt++) {                                               \
            int rb2 = nt * 16 + lane15;                                                \
            bfm[nt] = *(const short8*)&Bc[rb2 * 32 + (((quad + (rb2 >> 1)) & 3) << 3)];\
        }                                                                              \
        _Pragma("unroll")                                                              \
        for (int mt = 0; mt < 2; mt++)                                                 \
            _Pragma("unroll")                                                          \
            for (int nt = 0; nt < 4; nt++)                                             \
                acc[mt][nt] = __builtin_amdgcn_mfma_f32_16x16x32_bf16(af[mt], bfm[nt], acc[mt][nt], 0, 0, 0); \
    }

// ---------------- qkv GEMM: writes Q->qbuf(bf16), K->kh, V->vtb(f16) ----------------
__global__ __launch_bounds__(256) void gemm_qkv_kernel(const ushort_t* __restrict__ A,
                                                       const ushort_t* __restrict__ BT,
                                                       ushort_t* __restrict__ qbuf,
                                                       ushort_t* __restrict__ kh,
                                                       ushort_t* __restrict__ vtb) {
    GEMM_LOOP3(A, BT, 768, 768, 0)
    int yb = blockIdx.y;
    if (yb < 12) {
#pragma unroll
        for (int mt = 0; mt < 2; mt++) {
            int r_base = row0 + wave * 32 + mt * 16 + quad * 4;
#pragma unroll
            for (int nt = 0; nt < 4; nt++) {
                int cc = col0 + nt * 16 + lane15;
#pragma unroll
                for (int r = 0; r < 4; r++)
                    qbuf[(size_t)(r_base + r) * 768 + cc] = f2bf(acc[mt][nt][r]);
            }
        }
    } else if (yb < 24) {
#pragma unroll
        for (int mt = 0; mt < 2; mt++) {
            int r_base = row0 + wave * 32 + mt * 16 + quad * 4;
#pragma unroll
            for (int nt = 0; nt < 4; nt++) {
                int colk = col0 - 768 + nt * 16 + lane15;
                int hh = colk >> 6, dd = colk & 63;
#pragma unroll
                for (int r = 0; r < 4; r++) {
                    int rr = r_base + r;
                    kh[((size_t)((rr >> 11) * NH + hh)) * 131072 + (size_t)(rr & 2047) * 64 + dd] =
                        f2bf(acc[mt][nt][r]);
                }
            }
        }
    } else {
#pragma unroll
        for (int mt = 0; mt < 2; mt++) {
            int r_base = row0 + wave * 32 + mt * 16 + quad * 4;
            int bb2 = r_base >> 11;
            int tt = r_base & 2047;
#pragma unroll
            for (int nt = 0; nt < 4; nt++) {
                int colv = col0 - 1536 + nt * 16 + lane15;
                int hh = colv >> 6, dd = colv & 63;
                size_t va = ((size_t)(bb2 * NH + hh)) * 131072 + (size_t)(tt >> 4) * 1024 +
                            (size_t)dd * 16 + (tt & 15);
                ushortx4 pv;
#pragma unroll
                for (int r = 0; r < 4; r++) pv[r] = f2h_bits(acc[mt][nt][r]);
                *(ushortx4*)&vtb[va] = pv;
            }
        }
    }
}

// ---------------- fc GEMM: +bias, tanh-GELU, bf16 out ----------------
__global__ __launch_bounds__(256) void gemm_gelu_kernel(const ushort_t* __restrict__ A,
                                                        const ushort_t* __restrict__ BT,
                                                        const float* __restrict__ bias,
                                                        ushort_t* __restrict__ Cout) {
    GEMM_LOOP3(A, BT, 768, 768, 0)
    const int N = 3072;
#pragma unroll
    for (int mt = 0; mt < 2; mt++) {
        int r_base = row0 + wave * 32 + mt * 16 + quad * 4;
#pragma unroll
        for (int nt = 0; nt < 4; nt++) {
            int cc = col0 + nt * 16 + lane15;
            float bvv = bias[cc];
#pragma unroll
            for (int r = 0; r < 4; r++) {
                float v = acc[mt][nt][r] + bvv;
                float y2 = v * (2.3022079f + 0.10294323f * v * v);
                float e = __builtin_amdgcn_exp2f(-y2);
                v = v * __builtin_amdgcn_rcpf(1.f + e);
                Cout[(size_t)(r_base + r) * N + cc] = f2bf(v);
            }
        }
    }
}

// ---------------- Split-K GEMM: P[z][M][N](bf16) ----------------
__global__ __launch_bounds__(256) void gemm_bt_split_kernel(const ushort_t* __restrict__ A,
                                                            const ushort_t* __restrict__ BT,
                                                            ushort_t* __restrict__ P,
                                                            int M, int N, int K, int klen) {
    int kz0 = blockIdx.z * klen;
    GEMM_LOOP3(A, BT, K, klen, kz0)
    ushort_t* Pz = P + (size_t)blockIdx.z * M * N;
#pragma unroll
    for (int mt = 0; mt < 2; mt++) {
        int r_base = row0 + wave * 32 + mt * 16 + quad * 4;
#pragma unroll
        for (int nt = 0; nt < 4; nt++) {
            int cc = col0 + nt * 16 + lane15;
#pragma unroll
            for (int r = 0; r < 4; r++)
                Pz[(size_t)(r_base + r) * N + cc] = f2bf(acc[mt][nt][r]);
        }
    }
}

// -------------- combine: x2 += bias + P0 + P1 (in place) --------------
__global__ __launch_bounds__(256) void combine_bias_res_kernel(float* __restrict__ x2,
                                                               const float* __restrict__ bias,
                                                               const ushort_t* __restrict__ P) {
    int i = blockIdx.x * 256 + threadIdx.x;
    int col = (i * 4) % C_DIM;
    floatx4 xv = *(const floatx4*)&x2[i * 4];
    floatx4 bv = *(const floatx4*)&bias[col];
    ushortx4 a = *(const ushortx4*)&P[i * 4];
    ushortx4 b = *(const ushortx4*)&P[3145728 + i * 4];
    floatx4 o;
#pragma unroll
    for (int j = 0; j < 4; j++) o[j] = xv[j] + bv[j] + bf2f(a[j]) + bf2f(b[j]);
    *(floatx4*)&x2[i * 4] = o;
}

// ---------------- Flash attention: balanced key-split chunks, dbuf LDS K/V ----------------
#define QSCALE 0.18033688f  // 0.125 * log2(e)
__global__ __launch_bounds__(256) void attn_kernel(const ushort_t* __restrict__ qbuf,
                                                   const ushort_t* __restrict__ kh,
                                                   const ushort_t* __restrict__ vtb,
                                                   ushort_t* __restrict__ y,
                                                   ushort_t* __restrict__ OP,
                                                   float* __restrict__ LP) {
    __shared__ ushort_t Kb[2][4096];
    __shared__ ushort_t Vb[2][4096];
    int tid = threadIdx.x;
    int lane = tid & 63, wave = tid >> 6;
    int lane15 = lane & 15, quad = lane >> 4;
    int c = blockIdx.x;               // 0..47: chunks (halves first = heavy-first)
    int h = blockIdx.y, b = blockIdx.z;
    int qt, t_start, t_end, half = 0;
    bool is_half;
    if (c < 32) {
        qt = 16 + (c >> 1);
        half = c & 1;
        int ntl = qt + 1, mid = ntl >> 1;
        t_start = half ? mid : 0;
        t_end = half ? ntl : mid;
        is_half = true;
    } else {
        qt = c - 32;
        t_start = 0;
        t_end = qt + 1;
        is_half = false;
    }
    int q0 = qt * 64;
    size_t hb = (size_t)(b * NH + h) * (T_SEQ * 64);
    const ushort_t* khb = kh + hb;
    const ushort_t* vtbb = vtb + hb;

    int q = q0 + wave * 16 + lane15;
    int qmax_wave = q0 + wave * 16 + 15;
    short8 qf[2];
#pragma unroll
    for (int cc2 = 0; cc2 < 2; cc2++) {
        ushort8 qv = *(const ushort8*)(qbuf + ((size_t)b * T_SEQ + q) * 768 + h * 64 + cc2 * 32 + quad * 8);
        short8 qs;
#pragma unroll
        for (int j = 0; j < 8; j++) qs[j] = (short)f2bf(bf2f(qv[j]) * QSCALE);
        qf[cc2] = qs;
    }

    floatx4 o[4];
    floatx4 zero = {0.f, 0.f, 0.f, 0.f};
#pragma unroll
    for (int nt = 0; nt < 4; nt++) o[nt] = zero;
    float l4[4] = {0.f, 0.f, 0.f, 0.f};

    int vsrc = lane ^ ((lane >> 3) & 1);

    {   // stage tile t_start into buffer (t_start&1)
        int kb = t_start * 64;
        int buf = t_start & 1;
        if (wave < 2) {
#pragma unroll
            for (int j = 0; j < 4; j++) {
                int r = wave * 4 + j;
                int i = r * 64 + lane;
                int key = i >> 3;
                int seg = ((i & 7) - (key & 7) + 8) & 7;
                gload_lds16(khb + (size_t)(kb + key) * 64 + seg * 8, &Kb[buf][(size_t)r * 512]);
            }
        } else {
#pragma unroll
            for (int j = 0; j < 4; j++) {
                int r = (wave - 2) * 4 + j;
                gload_lds16(vtbb + (size_t)(kb >> 4) * 1024 + (size_t)r * 512 + vsrc * 8,
                            &Vb[buf][(size_t)r * 512]);
            }
        }
    }

    for (int t = t_start; t < t_end; t++) {
        int kb = t * 64;
        int cur = t & 1;
        __syncthreads();
        if (t + 1 < t_end) {
            int kb2 = kb + 64;
            int nxt = cur ^ 1;
            if (wave < 2) {
#pragma unroll
                for (int j = 0; j < 4; j++) {
                    int r = wave * 4 + j;
                    int i = r * 64 + lane;
                    int key = i >> 3;
                    int seg = ((i & 7) - (key & 7) + 8) & 7;
                    gload_lds16(khb + (size_t)(kb2 + key) * 64 + seg * 8, &Kb[nxt][(size_t)r * 512]);
                }
            } else {
#pragma unroll
                for (int j = 0; j < 4; j++) {
                    int r = (wave - 2) * 4 + j;
                    gload_lds16(vtbb + (size_t)(kb2 >> 4) * 1024 + (size_t)r * 512 + vsrc * 8,
                                &Vb[nxt][(size_t)r * 512]);
                }
            }
        }

        if (kb <= qmax_wave) {
            const ushort_t* Kc = Kb[cur];
            const _Float16* Vc = (const _Float16*)Vb[cur];

            floatx4 s[4];
#pragma unroll
            for (int sb = 0; sb < 4; sb++) {
                int key = sb * 16 + lane15;
                int s0i = key * 8 + ((quad + key) & 7);
                int s1i = key * 8 + ((quad + 4 + key) & 7);
                short8 kf0 = *(const short8*)(Kc + (size_t)s0i * 8);
                short8 kf1 = *(const short8*)(Kc + (size_t)s1i * 8);
                floatx4 sv = zero;
                sv = __builtin_amdgcn_mfma_f32_16x16x32_bf16(kf0, qf[0], sv, 0, 0, 0);
                sv = __builtin_amdgcn_mfma_f32_16x16x32_bf16(kf1, qf[1], sv, 0, 0, 0);
                s[sb] = sv;
            }

            if (kb + 64 > qmax_wave) {
#pragma unroll
                for (int sb = 0; sb < 4; sb++)
#pragma unroll
                    for (int r = 0; r < 4; r++) {
                        int key = kb + sb * 16 + quad * 4 + r;
                        if (key > q) s[sb][r] = -INFINITY;
                    }
            }

            half4 pf[4];
#pragma unroll
            for (int sb = 0; sb < 4; sb++)
#pragma unroll
                for (int r = 0; r < 4; r++) {
                    float p = __builtin_amdgcn_exp2f(s[sb][r]);
                    l4[r] += p;
                    pf[sb][r] = (_Float16)p;
                }

#pragma unroll
            for (int sb = 0; sb < 4; sb++) {
#pragma unroll
                for (int nt = 0; nt < 4; nt++) {
                    int gg = sb * 128 + (nt * 16 + lane15) * 2 + (quad >> 1);
                    int ss = gg ^ ((gg >> 3) & 1);
                    half4 vf = *(const half4*)&Vc[(size_t)ss * 8 + (quad & 1) * 4];
                    o[nt] = __builtin_amdgcn_mfma_f32_16x16x16f16(vf, pf[sb], o[nt], 0, 0, 0);
                }
            }
        }
    }

    float l_i = (l4[0] + l4[1]) + (l4[2] + l4[3]);
    l_i += __shfl_xor(l_i, 16, 64);
    l_i += __shfl_xor(l_i, 32, 64);

    if (!is_half) {
        float rcp_w = 1.f / l_i;
        ushort_t* yb = y + (size_t)b * T_SEQ * 768;
#pragma unroll
        for (int nt = 0; nt < 4; nt++) {
            ushortx4 st;
#pragma unroll
            for (int r = 0; r < 4; r++) st[r] = f2bf(o[nt][r] * rcp_w);
            *(ushortx4*)&yb[(size_t)q * 768 + h * 64 + nt * 16 + quad * 4] = st;
        }
    } else {
        int tileIdx = (qt - 16) + 16 * (h + NH * b);
        ushort_t* Ob = OP + (size_t)(tileIdx * 2 + half) * 4096;   // f16 [d=64][q=64]
        float* Lb = LP + (size_t)(tileIdx * 2 + half) * 64;
        if (quad == 0) Lb[wave * 16 + lane15] = l_i;
#pragma unroll
        for (int nt = 0; nt < 4; nt++)
#pragma unroll
            for (int r = 0; r < 4; r++)
                Ob[(nt * 16 + quad * 4 + r) * 64 + wave * 16 + lane15] = f2h_bits(o[nt][r]);
    }
}

// ---- attn combine: y[qt tile] = (O0+O1)/(l0+l1) for split tiles (no-max softmax) ----
__global__ __launch_bounds__(256) void attn_combine_kernel(const ushort_t* __restrict__ OP,
                                                           const float* __restrict__ LP,
                                                           ushort_t* __restrict__ y) {
    int qt = 16 + blockIdx.x;
    int h = blockIdx.y, b = blockIdx.z;
    int tileIdx = blockIdx.x + 16 * (h + NH * b);
    const _Float16* O0 = (const _Float16*)(OP + (size_t)(tileIdx * 2) * 4096);
    const _Float16* O1 = O0 + 4096;
    const float* L0 = LP + (size_t)(tileIdx * 2) * 64;
    const float* L1 = L0 + 64;
    int tid = threadIdx.x;
    ushort_t* yb = y + ((size_t)b * T_SEQ + qt * 64) * 768 + h * 64;
#pragma unroll
    for (int i = 0; i < 16; i++) {
        int idx = tid + i * 256;
        int q = idx >> 6, d = idx & 63;
        float v = (float)O0[d * 64 + q] + (float)O1[d * 64 + q];
        float l = L0[q] + L1[q];
        yb[(size_t)q * 768 + d] = f2bf(v / l);
    }
}

extern "C" void kernel_launch(void* const* d_in, const int* in_sizes, int n_in,
                              void* d_out, int out_size, void* d_ws, size_t ws_size,
                              hipStream_t stream) {
    (void)in_sizes; (void)n_in; (void)out_size; (void)ws_size;
    const float* x      = (const float*)d_in[0];
    const float* ln1_g  = (const float*)d_in[1];
    const float* ln1_b  = (const float*)d_in[2];
    const float* w_qkv  = (const float*)d_in[3];
    const float* w_o    = (const float*)d_in[4];
    const float* ln2_g  = (const float*)d_in[5];
    const float* ln2_b  = (const float*)d_in[6];
    const float* w_fc   = (const float*)d_in[7];
    const float* b_fc   = (const float*)d_in[8];
    const float* w_proj = (const float*)d_in[9];
    const float* b_proj = (const float*)d_in[10];

    char* ws = (char*)d_ws;
    // Region plan (bytes), peak 45,613,056 (43.5 MB):
    //   [0,        6291456)  qbuf   } PA (3x6291456) after attn; hff after combine_ln
    //   [6291456,  12582912) kh     }
    //   [12582912, 18874368) vtb    }
    //   [18874368, 25165824) ybuf   } hff tail
    //   [25165824, 31457280) xn -> attnO partials -> PB0
    //   [31457280, 34996224) wqkvT -> attnL partials -> PB1
    //   [34996224, 36175872) woT   -> PB1 tail
    //   [36175872, 40894464) wfcT  -> PB1 tail
    //   [40894464, 45613056) wprojT
    ushort_t* qbuf   = (ushort_t*)(ws);
    ushort_t* kh     = (ushort_t*)(ws + 6291456);
    ushort_t* vtb    = (ushort_t*)(ws + 12582912);
    ushort_t* PA     = (ushort_t*)(ws);
    ushort_t* hff    = (ushort_t*)(ws);
    ushort_t* ybuf   = (ushort_t*)(ws + 18874368);
    ushort_t* xn     = (ushort_t*)(ws + 25165824);
    ushort_t* attnO  = (ushort_t*)(ws + 25165824);
    float*    attnL  = (float*)(ws + 31457280);
    ushort_t* PB     = (ushort_t*)(ws + 25165824);
    ushort_t* wqkvT  = (ushort_t*)(ws + 31457280);
    ushort_t* woT    = (ushort_t*)(ws + 34996224);
    ushort_t* wfcT   = (ushort_t*)(ws + 36175872);
    ushort_t* wprojT = (ushort_t*)(ws + 40894464);
    float* x2 = (float*)d_out;

    const int M = NB * T_SEQ;  // 4096

    prep1_kernel<<<dim3(5824), 256, 0, stream>>>(w_qkv, wqkvT, w_o, woT, w_fc, wfcT,
                                                 w_proj, wprojT, x, ln1_g, ln1_b, xn);
    gemm_qkv_kernel<<<dim3(32, 36), 256, 0, stream>>>(xn, wqkvT, qbuf, kh, vtb);
    attn_kernel<<<dim3(48, 12, 2), 256, 0, stream>>>(qbuf, kh, vtb, ybuf, attnO, attnL);
    attn_combine_kernel<<<dim3(16, 12, 2), 256, 0, stream>>>(attnO, attnL, ybuf);
    gemm_bt_split_kernel<<<dim3(32, 12, 3), 256, 0, stream>>>(ybuf, woT, PA, M, 768, 768, 256);
    combine_ln_kernel<<<dim3(M), 192, 0, stream>>>(x, PA, ln2_g, ln2_b, x2, xn);
    gemm_gelu_kernel<<<dim3(32, 48), 256, 0, stream>>>(xn, wfcT, b_fc, hff);
    gemm_bt_split_kernel<<<dim3(32, 12, 2), 256, 0, stream>>>(hff, wprojT, PB, M, 768, 3072, 1536);
    combine_bias_res_kernel<<<dim3(3072), 256, 0, stream>>>(x2, b_proj, PB);
}

// Round 17
// 260.832 us; speedup vs baseline: 1.0455x; 1.0455x over previous
//
#include <hip/hip_runtime.h>
#include <hip/hip_bf16.h>
#include <math.h>

#define T_SEQ 2048
#define NB 2
#define C_DIM 768
#define NH 12

typedef unsigned short ushort_t;
typedef __attribute__((ext_vector_type(8))) short short8;
typedef __attribute__((ext_vector_type(8))) unsigned short ushort8;
typedef __attribute__((ext_vector_type(4))) unsigned short ushortx4;
typedef __attribute__((ext_vector_type(4))) float floatx4;
typedef __attribute__((ext_vector_type(4))) _Float16 half4;

__device__ inline float bf2f(ushort_t u) {
    unsigned int x = ((unsigned int)u) << 16;
    return __uint_as_float(x);
}
__device__ inline ushort_t f2bf(float f) {
    unsigned int u = __float_as_uint(f);
    unsigned int r = (u + 0x7fffu + ((u >> 16) & 1u)) >> 16;
    return (ushort_t)r;
}
__device__ inline ushort_t f2h_bits(float f) {
    union { _Float16 h; ushort_t u; } cv;
    cv.h = (_Float16)f;
    return cv.u;
}

#if defined(__has_builtin)
#if __has_builtin(__builtin_amdgcn_global_load_lds)
#define HAVE_GLL 1
#endif
#endif

__device__ inline void gload_lds16(const ushort_t* g, ushort_t* l) {
#ifdef HAVE_GLL
    __builtin_amdgcn_global_load_lds(
        (const __attribute__((address_space(1))) void*)g,
        (__attribute__((address_space(3))) void*)l, 16, 0, 0);
#else
    int lane = threadIdx.x & 63;
    *(ushort8*)(l + lane * 8) = *(const ushort8*)g;
#endif
}

// ------------- wconv tile: W[K][N] fp32 -> WT[N][K] bf16, one 64x64 tile -------------
__device__ void wconv_tile(const float* __restrict__ W, ushort_t* __restrict__ WT,
                           int K, int N, int k0, int n0, int tid, ushort_t* Tls) {
    int nl = (tid & 15) * 4;
    int kl = tid >> 4;
#pragma unroll
    for (int rr = 0; rr < 4; rr++) {
        int k = kl + rr * 16;
        floatx4 v = *(const floatx4*)&W[(size_t)(k0 + k) * N + n0 + nl];
#pragma unroll
        for (int j = 0; j < 4; j++) Tls[(nl + j) * 72 + k] = f2bf(v[j]);
    }
    __syncthreads();
    int no = tid >> 3;
    int ko = (tid & 7) * 8;
#pragma unroll
    for (int rr = 0; rr < 2; rr++) {
        int n = no + rr * 32;
        ushort8 t = *(const ushort8*)&Tls[n * 72 + ko];
        *(ushort8*)&WT[(size_t)(n0 + n) * K + k0 + ko] = t;
    }
}

// ---- prep1: all 4 weight conversions + LN1, routed by block range ----
__global__ __launch_bounds__(256) void prep1_kernel(const float* __restrict__ w_qkv, ushort_t* __restrict__ wqkvT,
                                                    const float* __restrict__ w_o, ushort_t* __restrict__ woT,
                                                    const float* __restrict__ w_fc, ushort_t* __restrict__ wfcT,
                                                    const float* __restrict__ w_proj, ushort_t* __restrict__ wprojT,
                                                    const float* __restrict__ x, const float* __restrict__ g,
                                                    const float* __restrict__ b, ushort_t* __restrict__ xn) {
    __shared__ ushort_t Tls[64 * 72];
    __shared__ float red[8];
    int id = blockIdx.x, tid = threadIdx.x;
    if (id < 432) { wconv_tile(w_qkv, wqkvT, 768, 2304, (id % 12) * 64, (id / 12) * 64, tid, Tls); return; }
    if (id < 576) { int r = id - 432; wconv_tile(w_o, woT, 768, 768, (r % 12) * 64, (r / 12) * 64, tid, Tls); return; }
    if (id < 1152) { int r = id - 576; wconv_tile(w_fc, wfcT, 768, 3072, (r % 12) * 64, (r / 12) * 64, tid, Tls); return; }
    if (id < 1728) { int r = id - 1152; wconv_tile(w_proj, wprojT, 3072, 768, (r % 48) * 64, (r / 48) * 64, tid, Tls); return; }
    int row = id - 1728;
    int lane = tid & 63, wave = tid >> 6;
    const float* xr = x + (size_t)row * C_DIM;
    float v0 = xr[tid], v1 = xr[tid + 256], v2 = xr[tid + 512];
    float s = v0 + v1 + v2;
#pragma unroll
    for (int m = 32; m > 0; m >>= 1) s += __shfl_xor(s, m, 64);
    if (lane == 0) red[wave] = s;
    __syncthreads();
    float mean = (red[0] + red[1] + red[2] + red[3]) * (1.0f / C_DIM);
    float d0 = v0 - mean, d1 = v1 - mean, d2 = v2 - mean;
    float q = d0 * d0 + d1 * d1 + d2 * d2;
#pragma unroll
    for (int m = 32; m > 0; m >>= 1) q += __shfl_xor(q, m, 64);
    if (lane == 0) red[wave + 4] = q;
    __syncthreads();
    float var = (red[4] + red[5] + red[6] + red[7]) * (1.0f / C_DIM);
    float rstd = rsqrtf(var + 1e-5f);
    ushort_t* orow = xn + (size_t)row * C_DIM;
    orow[tid]       = f2bf(d0 * rstd * g[tid]       + b[tid]);
    orow[tid + 256] = f2bf(d1 * rstd * g[tid + 256] + b[tid + 256]);
    orow[tid + 512] = f2bf(d2 * rstd * g[tid + 512] + b[tid + 512]);
}

// ---- Fused: x2 = x + P0+P1+P2 (fp32) then LayerNorm -> xn (bf16). 192 thr/row ----
__global__ __launch_bounds__(192) void combine_ln_kernel(const float* __restrict__ x,
                                                         const ushort_t* __restrict__ P,
                                                         const float* __restrict__ g,
                                                         const float* __restrict__ bb,
                                                         float* __restrict__ x2,
                                                         ushort_t* __restrict__ xn) {
    int row = blockIdx.x;
    int tid = threadIdx.x;
    int lane = tid & 63, wave = tid >> 6;
    int col = tid * 4;
    size_t idx = (size_t)row * C_DIM + col;
    floatx4 xv = *(const floatx4*)&x[idx];
    ushortx4 a = *(const ushortx4*)&P[idx];
    ushortx4 b2 = *(const ushortx4*)&P[3145728 + idx];
    ushortx4 c2 = *(const ushortx4*)&P[6291456 + idx];
    floatx4 v;
#pragma unroll
    for (int j = 0; j < 4; j++) v[j] = xv[j] + bf2f(a[j]) + bf2f(b2[j]) + bf2f(c2[j]);
    *(floatx4*)&x2[idx] = v;

    float s = v[0] + v[1] + v[2] + v[3];
#pragma unroll
    for (int m = 32; m > 0; m >>= 1) s += __shfl_xor(s, m, 64);
    __shared__ float red[6];
    if (lane == 0) red[wave] = s;
    __syncthreads();
    float mean = (red[0] + red[1] + red[2]) * (1.0f / C_DIM);
    floatx4 d;
#pragma unroll
    for (int j = 0; j < 4; j++) d[j] = v[j] - mean;
    float q = d[0] * d[0] + d[1] * d[1] + d[2] * d[2] + d[3] * d[3];
#pragma unroll
    for (int m = 32; m > 0; m >>= 1) q += __shfl_xor(q, m, 64);
    if (lane == 0) red[wave + 3] = q;
    __syncthreads();
    float var = (red[3] + red[4] + red[5]) * (1.0f / C_DIM);
    float rstd = rsqrtf(var + 1e-5f);
    floatx4 gv = *(const floatx4*)&g[col];
    floatx4 bv = *(const floatx4*)&bb[col];
    ushortx4 o;
#pragma unroll
    for (int j = 0; j < 4; j++) o[j] = f2bf(d[j] * rstd * gv[j] + bv[j]);
    *(ushortx4*)&xn[idx] = o;
}

// ======== GEMM K-loop v2: BK=32, double-buffered LDS via global_load_lds ========
#define GEMM_LOOP2(Aptr, Bptr, KDIM, KLEN, KOFF)                                       \
    __shared__ ushort_t As[2][4096];                                                   \
    __shared__ ushort_t Bs[2][4096];                                                   \
    int tid = threadIdx.x;                                                             \
    int lane = tid & 63, wave = tid >> 6;                                              \
    int lane15 = lane & 15, quad = lane >> 4;                                          \
    int wr = wave >> 1, wc = wave & 1;                                                 \
    int row0 = blockIdx.x * 128, col0 = blockIdx.y * 128;                              \
    const ushort_t* sp[4];                                                             \
    ushort_t* dp[2][4];                                                                \
    {                                                                                  \
        bool sA = (wave < 2);                                                          \
        int cw = sA ? wave : (wave - 2);                                               \
        const ushort_t* Mp = sA ? (Aptr) : (Bptr);                                     \
        int rb = sA ? row0 : col0;                                                     \
        _Pragma("unroll")                                                              \
        for (int j = 0; j < 4; j++) {                                                  \
            int c = cw * 4 + j;                                                        \
            int g = c * 64 + lane;                                                     \
            int row = g >> 2, j2 = g & 3;                                              \
            int s = (j2 - (row >> 1)) & 3;                                             \
            sp[j] = Mp + (size_t)(rb + row) * (KDIM) + (KOFF) + s * 8;                 \
            dp[0][j] = sA ? &As[0][c * 512] : &Bs[0][c * 512];                         \
            dp[1][j] = sA ? &As[1][c * 512] : &Bs[1][c * 512];                         \
        }                                                                              \
    }                                                                                  \
    floatx4 acc[4][4];                                                                 \
    {                                                                                  \
        floatx4 zz = {0.f, 0.f, 0.f, 0.f};                                             \
        _Pragma("unroll")                                                              \
        for (int mt = 0; mt < 4; mt++)                                                 \
            _Pragma("unroll")                                                          \
            for (int nt = 0; nt < 4; nt++) acc[mt][nt] = zz;                           \
    }                                                                                  \
    _Pragma("unroll")                                                                  \
    for (int j = 0; j < 4; j++) gload_lds16(sp[j], dp[0][j]);                          \
    int n_tiles = (KLEN) / 32;                                                         \
    for (int t = 0; t < n_tiles; t++) {                                                \
        int cur = t & 1;                                                               \
        __syncthreads();                                                               \
        if (t + 1 < n_tiles) {                                                         \
            _Pragma("unroll")                                                          \
            for (int j = 0; j < 4; j++)                                                \
                gload_lds16(sp[j] + (t + 1) * 32, dp[cur ^ 1][j]);                     \
        }                                                                              \
        const ushort_t* Ac = As[cur];                                                  \
        const ushort_t* Bc = Bs[cur];                                                  \
        short8 af[4], bfm[4];                                                          \
        _Pragma("unroll")                                                              \
        for (int mt = 0; mt < 4; mt++) {                                               \
            int ra = wr * 64 + mt * 16 + lane15;                                       \
            af[mt] = *(const short8*)&Ac[ra * 32 + (((quad + (ra >> 1)) & 3) << 3)];   \
        }                                                                              \
        _Pragma("unroll")                                                              \
        for (int nt = 0; nt < 4; nt++) {                                               \
            int rb2 = wc * 64 + nt * 16 + lane15;                                      \
            bfm[nt] = *(const short8*)&Bc[rb2 * 32 + (((quad + (rb2 >> 1)) & 3) << 3)];\
        }                                                                              \
        _Pragma("unroll")                                                              \
        for (int mt = 0; mt < 4; mt++)                                                 \
            _Pragma("unroll")                                                          \
            for (int nt = 0; nt < 4; nt++)                                             \
                acc[mt][nt] = __builtin_amdgcn_mfma_f32_16x16x32_bf16(af[mt], bfm[nt], acc[mt][nt], 0, 0, 0); \
    }

// ---------------- qkv GEMM: writes Q->qbuf(bf16), K->kh, V->vtb(f16) ----------------
__global__ __launch_bounds__(256) void gemm_qkv_kernel(const ushort_t* __restrict__ A,
                                                       const ushort_t* __restrict__ BT,
                                                       ushort_t* __restrict__ qbuf,
                                                       ushort_t* __restrict__ kh,
                                                       ushort_t* __restrict__ vtb) {
    GEMM_LOOP2(A, BT, 768, 768, 0)
    int yb = blockIdx.y;
    if (yb < 6) {
#pragma unroll
        for (int mt = 0; mt < 4; mt++) {
            int r_base = row0 + wr * 64 + mt * 16 + quad * 4;
#pragma unroll
            for (int nt = 0; nt < 4; nt++) {
                int cc = col0 + wc * 64 + nt * 16 + lane15;
#pragma unroll
                for (int r = 0; r < 4; r++)
                    qbuf[(size_t)(r_base + r) * 768 + cc] = f2bf(acc[mt][nt][r]);
            }
        }
    } else if (yb < 12) {
#pragma unroll
        for (int mt = 0; mt < 4; mt++) {
            int r_base = row0 + wr * 64 + mt * 16 + quad * 4;
#pragma unroll
            for (int nt = 0; nt < 4; nt++) {
                int colk = col0 - 768 + wc * 64 + nt * 16 + lane15;
                int hh = colk >> 6, dd = colk & 63;
#pragma unroll
                for (int r = 0; r < 4; r++) {
                    int rr = r_base + r;
                    kh[((size_t)((rr >> 11) * NH + hh)) * 131072 + (size_t)(rr & 2047) * 64 + dd] =
                        f2bf(acc[mt][nt][r]);
                }
            }
        }
    } else {
#pragma unroll
        for (int mt = 0; mt < 4; mt++) {
            int r_base = row0 + wr * 64 + mt * 16 + quad * 4;
            int bb2 = r_base >> 11;
            int tt = r_base & 2047;
#pragma unroll
            for (int nt = 0; nt < 4; nt++) {
                int colv = col0 - 1536 + wc * 64 + nt * 16 + lane15;
                int hh = colv >> 6, dd = colv & 63;
                size_t va = ((size_t)(bb2 * NH + hh)) * 131072 + (size_t)(tt >> 4) * 1024 +
                            (size_t)dd * 16 + (tt & 15);
                ushortx4 pv;
#pragma unroll
                for (int r = 0; r < 4; r++) pv[r] = f2h_bits(acc[mt][nt][r]);
                *(ushortx4*)&vtb[va] = pv;
            }
        }
    }
}

// ---------------- fc GEMM: +bias, tanh-GELU, bf16 out ----------------
__global__ __launch_bounds__(256) void gemm_gelu_kernel(const ushort_t* __restrict__ A,
                                                        const ushort_t* __restrict__ BT,
                                                        const float* __restrict__ bias,
                                                        ushort_t* __restrict__ Cout) {
    GEMM_LOOP2(A, BT, 768, 768, 0)
    const int N = 3072;
#pragma unroll
    for (int mt = 0; mt < 4; mt++) {
        int r_base = row0 + wr * 64 + mt * 16 + quad * 4;
#pragma unroll
        for (int nt = 0; nt < 4; nt++) {
            int cc = col0 + wc * 64 + nt * 16 + lane15;
            float bvv = bias[cc];
#pragma unroll
            for (int r = 0; r < 4; r++) {
                float v = acc[mt][nt][r] + bvv;
                float y2 = v * (2.3022079f + 0.10294323f * v * v);
                float e = __builtin_amdgcn_exp2f(-y2);
                v = v * __builtin_amdgcn_rcpf(1.f + e);
                Cout[(size_t)(r_base + r) * N + cc] = f2bf(v);
            }
        }
    }
}

// ---------------- Split-K GEMM: P[z][M][N](bf16) ----------------
__global__ __launch_bounds__(256) void gemm_bt_split_kernel(const ushort_t* __restrict__ A,
                                                            const ushort_t* __restrict__ BT,
                                                            ushort_t* __restrict__ P,
                                                            int M, int N, int K, int klen) {
    int kz0 = blockIdx.z * klen;
    GEMM_LOOP2(A, BT, K, klen, kz0)
    ushort_t* Pz = P + (size_t)blockIdx.z * M * N;
#pragma unroll
    for (int mt = 0; mt < 4; mt++) {
        int r_base = row0 + wr * 64 + mt * 16 + quad * 4;
#pragma unroll
        for (int nt = 0; nt < 4; nt++) {
            int cc = col0 + wc * 64 + nt * 16 + lane15;
#pragma unroll
            for (int r = 0; r < 4; r++)
                Pz[(size_t)(r_base + r) * N + cc] = f2bf(acc[mt][nt][r]);
        }
    }
}

// -------------- combine: x2 += bias + P0 + P1 (in place) --------------
__global__ __launch_bounds__(256) void combine_bias_res_kernel(float* __restrict__ x2,
                                                               const float* __restrict__ bias,
                                                               const ushort_t* __restrict__ P) {
    int i = blockIdx.x * 256 + threadIdx.x;
    int col = (i * 4) % C_DIM;
    floatx4 xv = *(const floatx4*)&x2[i * 4];
    floatx4 bv = *(const floatx4*)&bias[col];
    ushortx4 a = *(const ushortx4*)&P[i * 4];
    ushortx4 b = *(const ushortx4*)&P[3145728 + i * 4];
    floatx4 o;
#pragma unroll
    for (int j = 0; j < 4; j++) o[j] = xv[j] + bv[j] + bf2f(a[j]) + bf2f(b[j]);
    *(floatx4*)&x2[i * 4] = o;
}

// ---------------- Flash attention: 3-tier balanced key-split, dbuf LDS K/V ----------------
// qt 0..11 whole; qt 12..23 two chunks; qt 24..31 three chunks (max chunk 12 tiles).
// No-max softmax => partials combine by pure addition (O, l). Dispatch reversed: big first.
#define QSCALE 0.18033688f  // 0.125 * log2(e)
__global__ __launch_bounds__(256) void attn_kernel(const ushort_t* __restrict__ qbuf,
                                                   const ushort_t* __restrict__ kh,
                                                   const ushort_t* __restrict__ vtb,
                                                   ushort_t* __restrict__ y,
                                                   ushort_t* __restrict__ OP,
                                                   float* __restrict__ LP) {
    __shared__ ushort_t Kb[2][4096];
    __shared__ ushort_t Vb[2][4096];
    int tid = threadIdx.x;
    int lane = tid & 63, wave = tid >> 6;
    int lane15 = lane & 15, quad = lane >> 4;
    int c = 59 - (int)blockIdx.x;     // reversed: heavy chunks dispatch first
    int h = blockIdx.y, b = blockIdx.z;
    int qt, part, nsplit;
    if (c < 12) { qt = c; part = 0; nsplit = 1; }
    else if (c < 36) { qt = 12 + (c - 12) / 2; part = (c - 12) % 2; nsplit = 2; }
    else { qt = 24 + (c - 36) / 3; part = (c - 36) % 3; nsplit = 3; }
    int ntl = qt + 1;
    int t_start = part * ntl / nsplit;
    int t_end = (part + 1) * ntl / nsplit;
    bool is_partial = (nsplit > 1);

    int q0 = qt * 64;
    size_t hb = (size_t)(b * NH + h) * (T_SEQ * 64);
    const ushort_t* khb = kh + hb;
    const ushort_t* vtbb = vtb + hb;

    int q = q0 + wave * 16 + lane15;
    int qmax_wave = q0 + wave * 16 + 15;
    short8 qf[2];
#pragma unroll
    for (int cc2 = 0; cc2 < 2; cc2++) {
        ushort8 qv = *(const ushort8*)(qbuf + ((size_t)b * T_SEQ + q) * 768 + h * 64 + cc2 * 32 + quad * 8);
        short8 qs;
#pragma unroll
        for (int j = 0; j < 8; j++) qs[j] = (short)f2bf(bf2f(qv[j]) * QSCALE);
        qf[cc2] = qs;
    }

    floatx4 o[4];
    floatx4 zero = {0.f, 0.f, 0.f, 0.f};
#pragma unroll
    for (int nt = 0; nt < 4; nt++) o[nt] = zero;
    float l4[4] = {0.f, 0.f, 0.f, 0.f};

    int vsrc = lane ^ ((lane >> 3) & 1);

    {   // stage tile t_start into buffer (t_start&1)
        int kb = t_start * 64;
        int buf = t_start & 1;
        if (wave < 2) {
#pragma unroll
            for (int j = 0; j < 4; j++) {
                int r = wave * 4 + j;
                int i = r * 64 + lane;
                int key = i >> 3;
                int seg = ((i & 7) - (key & 7) + 8) & 7;
                gload_lds16(khb + (size_t)(kb + key) * 64 + seg * 8, &Kb[buf][(size_t)r * 512]);
            }
        } else {
#pragma unroll
            for (int j = 0; j < 4; j++) {
                int r = (wave - 2) * 4 + j;
                gload_lds16(vtbb + (size_t)(kb >> 4) * 1024 + (size_t)r * 512 + vsrc * 8,
                            &Vb[buf][(size_t)r * 512]);
            }
        }
    }

    for (int t = t_start; t < t_end; t++) {
        int kb = t * 64;
        int cur = t & 1;
        __syncthreads();
        if (t + 1 < t_end) {
            int kb2 = kb + 64;
            int nxt = cur ^ 1;
            if (wave < 2) {
#pragma unroll
                for (int j = 0; j < 4; j++) {
                    int r = wave * 4 + j;
                    int i = r * 64 + lane;
                    int key = i >> 3;
                    int seg = ((i & 7) - (key & 7) + 8) & 7;
                    gload_lds16(khb + (size_t)(kb2 + key) * 64 + seg * 8, &Kb[nxt][(size_t)r * 512]);
                }
            } else {
#pragma unroll
                for (int j = 0; j < 4; j++) {
                    int r = (wave - 2) * 4 + j;
                    gload_lds16(vtbb + (size_t)(kb2 >> 4) * 1024 + (size_t)r * 512 + vsrc * 8,
                                &Vb[nxt][(size_t)r * 512]);
                }
            }
        }

        if (kb <= qmax_wave) {
            const ushort_t* Kc = Kb[cur];
            const _Float16* Vc = (const _Float16*)Vb[cur];

            floatx4 s[4];
#pragma unroll
            for (int sb = 0; sb < 4; sb++) {
                int key = sb * 16 + lane15;
                int s0i = key * 8 + ((quad + key) & 7);
                int s1i = key * 8 + ((quad + 4 + key) & 7);
                short8 kf0 = *(const short8*)(Kc + (size_t)s0i * 8);
                short8 kf1 = *(const short8*)(Kc + (size_t)s1i * 8);
                floatx4 sv = zero;
                sv = __builtin_amdgcn_mfma_f32_16x16x32_bf16(kf0, qf[0], sv, 0, 0, 0);
                sv = __builtin_amdgcn_mfma_f32_16x16x32_bf16(kf1, qf[1], sv, 0, 0, 0);
                s[sb] = sv;
            }

            if (kb + 64 > qmax_wave) {  // only the diagonal tile (in the last part) masks
#pragma unroll
                for (int sb = 0; sb < 4; sb++)
#pragma unroll
                    for (int r = 0; r < 4; r++) {
                        int key = kb + sb * 16 + quad * 4 + r;
                        if (key > q) s[sb][r] = -INFINITY;
                    }
            }

            half4 pf[4];
#pragma unroll
            for (int sb = 0; sb < 4; sb++)
#pragma unroll
                for (int r = 0; r < 4; r++) {
                    float p = __builtin_amdgcn_exp2f(s[sb][r]);
                    l4[r] += p;
                    pf[sb][r] = (_Float16)p;
                }

#pragma unroll
            for (int sb = 0; sb < 4; sb++) {
#pragma unroll
                for (int nt = 0; nt < 4; nt++) {
                    int gg = sb * 128 + (nt * 16 + lane15) * 2 + (quad >> 1);
                    int ss = gg ^ ((gg >> 3) & 1);
                    half4 vf = *(const half4*)&Vc[(size_t)ss * 8 + (quad & 1) * 4];
                    o[nt] = __builtin_amdgcn_mfma_f32_16x16x16f16(vf, pf[sb], o[nt], 0, 0, 0);
                }
            }
        }
    }

    float l_i = (l4[0] + l4[1]) + (l4[2] + l4[3]);
    l_i += __shfl_xor(l_i, 16, 64);
    l_i += __shfl_xor(l_i, 32, 64);

    if (!is_partial) {
        float rcp_w = 1.f / l_i;
        ushort_t* yb = y + (size_t)b * T_SEQ * 768;
#pragma unroll
        for (int nt = 0; nt < 4; nt++) {
            ushortx4 st;
#pragma unroll
            for (int r = 0; r < 4; r++) st[r] = f2bf(o[nt][r] * rcp_w);
            *(ushortx4*)&yb[(size_t)q * 768 + h * 64 + nt * 16 + quad * 4] = st;
        }
    } else {
        int slot = (qt < 24) ? (qt - 12) * 2 + part : 24 + (qt - 24) * 3 + part;  // 0..47
        int tileIdx = slot + 48 * (h + NH * b);
        ushort_t* Ob = OP + (size_t)tileIdx * 4096;   // f16 [d=64][q=64]
        float* Lb = LP + (size_t)tileIdx * 64;
        if (quad == 0) Lb[wave * 16 + lane15] = l_i;
#pragma unroll
        for (int nt = 0; nt < 4; nt++)
#pragma unroll
            for (int r = 0; r < 4; r++)
                Ob[(nt * 16 + quad * 4 + r) * 64 + wave * 16 + lane15] = f2h_bits(o[nt][r]);
    }
}

// ---- attn combine: y[qt tile] = sum_p O_p / sum_p l_p  for split tiles (qt >= 12) ----
__global__ __launch_bounds__(256) void attn_combine_kernel(const ushort_t* __restrict__ OP,
                                                           const float* __restrict__ LP,
                                                           ushort_t* __restrict__ y) {
    int qt = 12 + blockIdx.x;          // 12..31
    int h = blockIdx.y, b = blockIdx.z;
    int nsplit = (qt < 24) ? 2 : 3;
    int slot0 = (qt < 24) ? (qt - 12) * 2 : 24 + (qt - 24) * 3;
    int base = 48 * (h + NH * b);
    const _Float16* O0 = (const _Float16*)(OP + (size_t)(base + slot0) * 4096);
    const float* L0 = LP + (size_t)(base + slot0) * 64;
    int tid = threadIdx.x;
    ushort_t* yb = y + ((size_t)b * T_SEQ + qt * 64) * 768 + h * 64;
#pragma unroll
    for (int i = 0; i < 16; i++) {
        int idx = tid + i * 256;
        int q = idx >> 6, d = idx & 63;
        float v = (float)O0[d * 64 + q] + (float)O0[4096 + d * 64 + q];
        float l = L0[q] + L0[64 + q];
        if (nsplit == 3) { v += (float)O0[8192 + d * 64 + q]; l += L0[128 + q]; }
        yb[(size_t)q * 768 + d] = f2bf(v / l);
    }
}

extern "C" void kernel_launch(void* const* d_in, const int* in_sizes, int n_in,
                              void* d_out, int out_size, void* d_ws, size_t ws_size,
                              hipStream_t stream) {
    (void)in_sizes; (void)n_in; (void)out_size; (void)ws_size;
    const float* x      = (const float*)d_in[0];
    const float* ln1_g  = (const float*)d_in[1];
    const float* ln1_b  = (const float*)d_in[2];
    const float* w_qkv  = (const float*)d_in[3];
    const float* w_o    = (const float*)d_in[4];
    const float* ln2_g  = (const float*)d_in[5];
    const float* ln2_b  = (const float*)d_in[6];
    const float* w_fc   = (const float*)d_in[7];
    const float* b_fc   = (const float*)d_in[8];
    const float* w_proj = (const float*)d_in[9];
    const float* b_proj = (const float*)d_in[10];

    char* ws = (char*)d_ws;
    // Region plan (bytes), peak 45,613,056 (43.5 MB):
    //   [0,        6291456)  qbuf   } PA (3x6291456) after attn; hff after combine_ln
    //   [6291456,  12582912) kh     }
    //   [12582912, 18874368) vtb    }
    //   [18874368, 25165824) ybuf   } hff tail
    //   [25165824, 34603008) xn(first 6.29MB) -> attnO partials (9.44MB over xn+wqkvT) -> PB
    //   [34603008, 34897920) attnL partials (in dead wqkvT tail)
    //   [31457280, 34996224) wqkvT (dead after qkv GEMM)
    //   [34996224, 36175872) woT
    //   [36175872, 40894464) wfcT
    //   [40894464, 45613056) wprojT
    ushort_t* qbuf   = (ushort_t*)(ws);
    ushort_t* kh     = (ushort_t*)(ws + 6291456);
    ushort_t* vtb    = (ushort_t*)(ws + 12582912);
    ushort_t* PA     = (ushort_t*)(ws);
    ushort_t* hff    = (ushort_t*)(ws);
    ushort_t* ybuf   = (ushort_t*)(ws + 18874368);
    ushort_t* xn     = (ushort_t*)(ws + 25165824);
    ushort_t* attnO  = (ushort_t*)(ws + 25165824);
    float*    attnL  = (float*)(ws + 34603008);
    ushort_t* PB     = (ushort_t*)(ws + 25165824);
    ushort_t* wqkvT  = (ushort_t*)(ws + 31457280);
    ushort_t* woT    = (ushort_t*)(ws + 34996224);
    ushort_t* wfcT   = (ushort_t*)(ws + 36175872);
    ushort_t* wprojT = (ushort_t*)(ws + 40894464);
    float* x2 = (float*)d_out;

    const int M = NB * T_SEQ;  // 4096

    prep1_kernel<<<dim3(5824), 256, 0, stream>>>(w_qkv, wqkvT, w_o, woT, w_fc, wfcT,
                                                 w_proj, wprojT, x, ln1_g, ln1_b, xn);
    gemm_qkv_kernel<<<dim3(32, 18), 256, 0, stream>>>(xn, wqkvT, qbuf, kh, vtb);
    attn_kernel<<<dim3(60, 12, 2), 256, 0, stream>>>(qbuf, kh, vtb, ybuf, attnO, attnL);
    attn_combine_kernel<<<dim3(20, 12, 2), 256, 0, stream>>>(attnO, attnL, ybuf);
    gemm_bt_split_kernel<<<dim3(32, 6, 3), 256, 0, stream>>>(ybuf, woT, PA, M, 768, 768, 256);
    combine_ln_kernel<<<dim3(M), 192, 0, stream>>>(x, PA, ln2_g, ln2_b, x2, xn);
    gemm_gelu_kernel<<<dim3(32, 24), 256, 0, stream>>>(xn, wfcT, b_fc, hff);
    gemm_bt_split_kernel<<<dim3(32, 6, 2), 256, 0, stream>>>(hff, wprojT, PB, M, 768, 3072, 1536);
    combine_bias_res_kernel<<<dim3(3072), 256, 0, stream>>>(x2, b_proj, PB);
}